// Round 5
// baseline (236.492 us; speedup 1.0000x reference)
//
#include <hip/hip_runtime.h>
#include <hip/hip_bf16.h>
#include <stdint.h>

typedef __attribute__((ext_vector_type(8))) short short8;
typedef __attribute__((ext_vector_type(8))) unsigned short ushort8;
typedef __attribute__((ext_vector_type(4))) unsigned short ushort4v;
typedef __attribute__((ext_vector_type(4))) float f32x4;
typedef __attribute__((ext_vector_type(16))) float f32x16;

#define B_ 8
#define N_ 4096
#define C_ 256
#define D_ 32
#define LOG2E 1.44269504088896f

__device__ inline unsigned short f2bf(float f) {
  union { float f; unsigned u; } v; v.f = f;
  unsigned r = v.u + 0x7fffu + ((v.u >> 16) & 1u);
  return (unsigned short)(r >> 16);
}
__device__ inline float bf2f(unsigned short u) {
  return __uint_as_float(((unsigned)u) << 16);
}
__device__ inline float exp2_fast(float x) {
  float r; asm("v_exp_f32 %0, %1" : "=v"(r) : "v"(x)); return r;
}
__device__ inline unsigned cvt_pk_bf16(float lo, float hi) {
  unsigned r; asm("v_cvt_pk_bf16_f32 %0, %1, %2" : "=v"(r) : "v"(lo), "v"(hi)); return r;
}
// a <- [a.l0-31 | b.l0-31], b <- [a.l32-63 | b.l32-63]
__device__ inline void permlane32_swap(unsigned& a, unsigned& b) {
  asm volatile("v_permlane32_swap_b32 %0, %1" : "+v"(a), "+v"(b));
}
__device__ inline void gll16(const unsigned short* src, void* lds) {
  __builtin_amdgcn_global_load_lds((const __attribute__((address_space(1))) void*)src,
                                   (__attribute__((address_space(3))) void*)lds, 16, 0, 0);
}

// ---------------- kernel 0: weight cast+transpose ----------------
// wcomb[320][256]: rows 0-31 w_q^T*log2e | 32-63 w_k^T | 64-319 w_v^T. woT[256][256].
__global__ __launch_bounds__(256) void prep_kernel(const float* __restrict__ wq,
                                                   const float* __restrict__ wk,
                                                   const float* __restrict__ wv,
                                                   const float* __restrict__ wo,
                                                   unsigned short* __restrict__ wcomb,
                                                   unsigned short* __restrict__ woT) {
  int i = blockIdx.x * 256 + threadIdx.x;  // total 147456
  if (i < 81920) {
    int row = i >> 8, kk = i & 255;
    float v;
    if (row < 32)       v = wq[kk * 32 + row] * LOG2E;
    else if (row < 64)  v = wk[kk * 32 + (row - 32)];
    else                v = wv[kk * 256 + (row - 64)];
    wcomb[i] = f2bf(v);
  } else {
    int j = i - 81920;  // woT[c][e] = wo[e][c]
    int c = j >> 8, e = j & 255;
    woT[j] = f2bf(wo[e * 256 + c]);
  }
}

// ---------------- kernel 1: QKV projection GEMM (x staged via LDS, coalesced) ----
__global__ __launch_bounds__(256, 4) void qkv_kernel(const float* __restrict__ x,
                                                     const unsigned short* __restrict__ wcomb,
                                                     unsigned short* __restrict__ q,
                                                     unsigned short* __restrict__ k,
                                                     unsigned short* __restrict__ vT) {
  __shared__ __align__(16) unsigned short xs[64 * 256];  // 32KB, swizzled
  const int tid = threadIdx.x;
  const int lane = tid & 63, w = tid >> 6;
  const int bx = blockIdx.x;
  const int g = lane >> 4, li = lane & 15;
  const int m0 = bx * 64;

  // stage x[64][256] -> bf16 LDS, fully coalesced (32B/thread/round)
#pragma unroll
  for (int r = 0; r < 8; ++r) {
    int idx8 = r * 256 + tid;          // 8-elem block index
    int row = idx8 >> 5, blk = idx8 & 31;
    const float* src = x + (size_t)(m0 + row) * 256 + blk * 8;
    f32x4 a0 = *reinterpret_cast<const f32x4*>(src);
    f32x4 a1 = *reinterpret_cast<const f32x4*>(src + 4);
    ushort8 pk;
    pk[0] = f2bf(a0[0]); pk[1] = f2bf(a0[1]); pk[2] = f2bf(a0[2]); pk[3] = f2bf(a0[3]);
    pk[4] = f2bf(a1[0]); pk[5] = f2bf(a1[1]); pk[6] = f2bf(a1[2]); pk[7] = f2bf(a1[3]);
    *reinterpret_cast<ushort8*>(&xs[row * 256 + ((blk ^ (row & 7)) << 3)]) = pk;
  }
  __syncthreads();

  const unsigned short* wrow = wcomb + (size_t)li * 256 + (g << 3);
  f32x4 acc[20] = {};
  for (int kk = 0; kk < 256; kk += 32) {
    const int row = w * 16 + li;
    short8 a = *reinterpret_cast<const short8*>(
        &xs[row * 256 + ((((kk >> 3) + g) ^ (row & 7)) << 3)]);
#pragma unroll
    for (int ct = 0; ct < 20; ++ct) {
      short8 bb = *reinterpret_cast<const short8*>(wrow + (size_t)ct * 16 * 256 + kk);
      acc[ct] = __builtin_amdgcn_mfma_f32_16x16x32_bf16(a, bb, acc[ct], 0, 0, 0);
    }
  }
  const int bb_ = bx >> 6;
  const int nloc = (bx & 63) * 64 + w * 16 + (g << 2);
#pragma unroll
  for (int ct = 0; ct < 4; ++ct) {
    int col = ct * 16 + li;
    unsigned short* dst = (ct < 2) ? q : k;
    int cc = (ct < 2) ? col : col - 32;
#pragma unroll
    for (int r = 0; r < 4; ++r)
      dst[((size_t)bb_ * N_ + nloc + r) * D_ + cc] = f2bf(acc[ct][r]);
  }
#pragma unroll
  for (int ct = 4; ct < 20; ++ct) {
    int vcol = (ct - 4) * 16 + li;
    ushort4v pk;
    pk[0] = f2bf(acc[ct][0]); pk[1] = f2bf(acc[ct][1]);
    pk[2] = f2bf(acc[ct][2]); pk[3] = f2bf(acc[ct][3]);
    *reinterpret_cast<ushort4v*>(&vT[((size_t)bb_ * C_ + vcol) * N_ + nloc]) = pk;
  }
}

// ---------------- kernel 2: flash attention ----------------
// grid 2048 x 128 threads: blk = ((qt*2+ch)*2+kvh)*8 + b  (blk%8 = b -> XCD pin).
// Block = 2 waves (qg), each wave 32q x 128c x 2048kv. Chunk 32 kv, double-buffered
// shared V[128c][32kv] + K[32kv][32d] in LDS. Per iter: syncthreads (drains prior
// stage, proves partner done reading buf^1) -> STAGE(buf^1) -> compute(buf).
// P stays in registers (swapped S^T = K.Q^T, fixed m=0, q pre-scaled log2e).
__global__ __launch_bounds__(128, 3) void flash_kernel(const unsigned short* __restrict__ q,
                                                       const unsigned short* __restrict__ k,
                                                       const unsigned short* __restrict__ vT,
                                                       unsigned short* __restrict__ opart,
                                                       float* __restrict__ lsumpart) {
  __shared__ __align__(16) char smem[20480];  // V 2x8192 @0 | K 2x2048 @16384
  const int tid = threadIdx.x;
  const int l = tid & 63, w_ = tid >> 6;
  const int blk = blockIdx.x;
  const int b = blk & 7;
  const int t_ = blk >> 3;
  const int kvh = t_ & 1, ch = (t_ >> 1) & 1, qt = t_ >> 2;  // qt 0..63
  const int h = l >> 5, l31 = l & 31;

  const unsigned short* kb_ = k + (size_t)b * N_ * D_;
  const unsigned short* vb_ = vT + (size_t)b * C_ * N_;

  // Q B-frags: col q = l31, k = ks*16 + 8h + j
  const int qpos = qt * 64 + w_ * 32 + l31;
  const size_t qoff = ((size_t)b * N_ + qpos) * D_ + h * 8;
  const short8 qb0 = *reinterpret_cast<const short8*>(q + qoff);
  const short8 qb1 = *reinterpret_cast<const short8*>(q + qoff + 16);

  // staging lane constants: row = l>>2, LDS blk = l&3 holds data blk (l&3)^((l>>3)&3)
  const int stg_row = l >> 2;
  const int stg_bk = ((l & 3) ^ ((l >> 3) & 3)) << 3;  // elems

#define STAGE(BUF, KV0)                                                              \
  {                                                                                  \
    _Pragma("unroll") for (int jj = 0; jj < 4; ++jj) {                               \
      const int cl = w_ * 64 + jj * 16;                                              \
      gll16(vb_ + (size_t)(ch * 128 + cl + stg_row) * N_ + (KV0) + stg_bk,           \
            smem + (BUF)*8192 + cl * 64);                                            \
    }                                                                                \
    gll16(kb_ + (size_t)((KV0) + w_ * 16 + stg_row) * D_ + stg_bk,                   \
          smem + 16384 + (BUF)*2048 + w_ * 16 * 64);                                 \
  }

  f32x16 o[4] = {};  // [ct]: O^T tile (32c x 32q)
  float lsum = 0.f;
  const f32x16 z16 = {};
  const int kvbase = kvh * 2048;

  STAGE(0, kvbase)

  for (int i = 0; i < 64; ++i) {
    const int buf = i & 1;
    __syncthreads();  // buf ready (vmcnt0 drain); partner done reading buf^1
    if (i < 63) STAGE(buf ^ 1, kvbase + i * 32 + 32)
    const char* Vb = smem + buf * 8192;
    const char* Kb = smem + 16384 + buf * 2048;
    // S^T[32kv][32q] = K . Q^T
    const int kkey = (l31 >> 1) & 3;
    short8 ka0 = *reinterpret_cast<const short8*>(Kb + l31 * 64 + (((0 + h) ^ kkey) << 4));
    short8 ka1 = *reinterpret_cast<const short8*>(Kb + l31 * 64 + (((2 + h) ^ kkey) << 4));
    f32x16 s = __builtin_amdgcn_mfma_f32_32x32x16_bf16(ka0, qb0, z16, 0, 0, 0);
    s = __builtin_amdgcn_mfma_f32_32x32x16_bf16(ka1, qb1, s, 0, 0, 0);
    float p[16];
#pragma unroll
    for (int r = 0; r < 16; ++r) p[r] = exp2_fast(s[r]);
    lsum += (((p[0] + p[1]) + (p[2] + p[3])) + ((p[4] + p[5]) + (p[6] + p[7]))) +
            (((p[8] + p[9]) + (p[10] + p[11])) + ((p[12] + p[13]) + (p[14] + p[15])));
    // pack P^T into PV B-frags (validated r3/r4 path)
    unsigned x0 = cvt_pk_bf16(p[0], p[1]),   y0 = cvt_pk_bf16(p[4], p[5]);
    unsigned x1 = cvt_pk_bf16(p[2], p[3]),   y1 = cvt_pk_bf16(p[6], p[7]);
    unsigned x2 = cvt_pk_bf16(p[8], p[9]),   y2 = cvt_pk_bf16(p[12], p[13]);
    unsigned x3 = cvt_pk_bf16(p[10], p[11]), y3 = cvt_pk_bf16(p[14], p[15]);
    permlane32_swap(x0, y0); permlane32_swap(x1, y1);
    permlane32_swap(x2, y2); permlane32_swap(x3, y3);
    union U { unsigned u[4]; short8 v; };
    U u0; u0.u[0] = x0; u0.u[1] = x1; u0.u[2] = y0; u0.u[3] = y1;  // kv 0-15
    U u1; u1.u[0] = x2; u1.u[1] = x3; u1.u[2] = y2; u1.u[3] = y3;  // kv 16-31
    // PV: O^T[c][q] += V^T . P^T
    __builtin_amdgcn_s_setprio(1);
#pragma unroll
    for (int ct = 0; ct < 4; ++ct) {
      const int rl = ct * 32 + l31;
      const int vkey = (rl >> 1) & 3;
      short8 va0 = *reinterpret_cast<const short8*>(Vb + rl * 64 + (((0 + h) ^ vkey) << 4));
      short8 va1 = *reinterpret_cast<const short8*>(Vb + rl * 64 + (((2 + h) ^ vkey) << 4));
      o[ct] = __builtin_amdgcn_mfma_f32_32x32x16_bf16(va0, u0.v, o[ct], 0, 0, 0);
      o[ct] = __builtin_amdgcn_mfma_f32_32x32x16_bf16(va1, u1.v, o[ct], 0, 0, 0);
    }
    __builtin_amdgcn_s_setprio(0);
  }

  // ---- epilogue: unnormalized bf16 O partial + f32 lsum partial ----
  lsum += __shfl_xor(lsum, 32);
  unsigned short* op = opart + (size_t)kvh * B_ * N_ * C_;
  const size_t rowoff = ((size_t)b * N_ + qpos) * C_ + ch * 128;
#pragma unroll
  for (int ct = 0; ct < 4; ++ct)
#pragma unroll
    for (int j = 0; j < 8; ++j) {
      const int c = ct * 32 + 2 * (j & 1) + 8 * (j >> 1) + 4 * h;
      unsigned wv = cvt_pk_bf16(o[ct][2 * j], o[ct][2 * j + 1]);
      *reinterpret_cast<unsigned*>(&op[rowoff + c]) = wv;
    }
  if (h == 0)
    lsumpart[(size_t)kvh * B_ * N_ + b * N_ + qpos] = lsum;
#undef STAGE
}

// ---------------- kernel 3: merge partials + output projection + residual --------
__global__ __launch_bounds__(256, 4) void out_kernel(const unsigned short* __restrict__ opart,
                                                     const float* __restrict__ lsumpart,
                                                     const unsigned short* __restrict__ woT,
                                                     const float* __restrict__ x,
                                                     float* __restrict__ out) {
  const int lane = threadIdx.x & 63, w = threadIdx.x >> 6;
  const int bx = blockIdx.x;
  const int g = lane >> 4, li = lane & 15;
  const int m0 = bx * 64 + w * 16;
  const int m = m0 + li;
  const float inv = 1.0f / (lsumpart[m] + lsumpart[B_ * N_ + m]);
  const unsigned short* arow0 = opart + (size_t)m * 256 + (g << 3);
  const unsigned short* arow1 = arow0 + (size_t)B_ * N_ * C_;
  const unsigned short* wrow = woT + (size_t)li * 256 + (g << 3);
  f32x4 acc[16] = {};
  for (int kk = 0; kk < 256; kk += 32) {
    ushort8 a0 = *reinterpret_cast<const ushort8*>(arow0 + kk);
    ushort8 a1 = *reinterpret_cast<const ushort8*>(arow1 + kk);
    short8 a;
#pragma unroll
    for (int e = 0; e < 8; ++e)
      a[e] = (short)f2bf((bf2f(a0[e]) + bf2f(a1[e])) * inv);
#pragma unroll
    for (int ct = 0; ct < 16; ++ct) {
      short8 bb = *reinterpret_cast<const short8*>(wrow + (size_t)ct * 16 * 256 + kk);
      acc[ct] = __builtin_amdgcn_mfma_f32_16x16x32_bf16(a, bb, acc[ct], 0, 0, 0);
    }
  }
#pragma unroll
  for (int ct = 0; ct < 16; ++ct) {
    int col = ct * 16 + li;
#pragma unroll
    for (int r = 0; r < 4; ++r) {
      size_t idx = (size_t)(m0 + (g << 2) + r) * 256 + col;
      out[idx] = acc[ct][r] + x[idx];
    }
  }
}

extern "C" void kernel_launch(void* const* d_in, const int* in_sizes, int n_in,
                              void* d_out, int out_size, void* d_ws, size_t ws_size,
                              hipStream_t stream) {
  const float* x  = (const float*)d_in[0];
  const float* wq = (const float*)d_in[1];
  const float* wk = (const float*)d_in[2];
  const float* wv = (const float*)d_in[3];
  const float* wo = (const float*)d_in[4];
  float* out = (float*)d_out;
  char* ws = (char*)d_ws;
  unsigned short* wcomb = (unsigned short*)(ws + 0);          // 163840 B
  unsigned short* woT   = (unsigned short*)(ws + 163840);     // 131072 B
  unsigned short* q     = (unsigned short*)(ws + 294912);     // 2 MB
  unsigned short* k     = (unsigned short*)(ws + 2392064);    // 2 MB
  unsigned short* vT    = (unsigned short*)(ws + 4489216);    // 16 MB
  unsigned short* opart = (unsigned short*)(ws + 21266432);   // 32 MB (2 parts)
  float*          lsump = (float*)(ws + 54820864);            // 256 KB

  prep_kernel<<<576, 256, 0, stream>>>(wq, wk, wv, wo, wcomb, woT);
  qkv_kernel<<<512, 256, 0, stream>>>(x, wcomb, q, k, vT);
  flash_kernel<<<2048, 128, 0, stream>>>(q, k, vT, opart, lsump);
  out_kernel<<<512, 256, 0, stream>>>(opart, lsump, woT, x, out);
}

// Round 6
// 209.842 us; speedup vs baseline: 1.1270x; 1.1270x over previous
//
#include <hip/hip_runtime.h>
#include <hip/hip_bf16.h>
#include <stdint.h>

typedef __attribute__((ext_vector_type(8))) short short8;
typedef __attribute__((ext_vector_type(8))) unsigned short ushort8;
typedef __attribute__((ext_vector_type(4))) unsigned short ushort4v;
typedef __attribute__((ext_vector_type(4))) float f32x4;
typedef __attribute__((ext_vector_type(16))) float f32x16;

#define B_ 8
#define N_ 4096
#define C_ 256
#define D_ 32
#define LOG2E 1.44269504088896f

__device__ inline unsigned short f2bf(float f) {
  union { float f; unsigned u; } v; v.f = f;
  unsigned r = v.u + 0x7fffu + ((v.u >> 16) & 1u);
  return (unsigned short)(r >> 16);
}
__device__ inline float exp2_fast(float x) {
  float r; asm("v_exp_f32 %0, %1" : "=v"(r) : "v"(x)); return r;
}
__device__ inline unsigned cvt_pk_bf16(float lo, float hi) {
  unsigned r; asm("v_cvt_pk_bf16_f32 %0, %1, %2" : "=v"(r) : "v"(lo), "v"(hi)); return r;
}
// a <- [a.l0-31 | b.l0-31], b <- [a.l32-63 | b.l32-63]
__device__ inline void permlane32_swap(unsigned& a, unsigned& b) {
  asm volatile("v_permlane32_swap_b32 %0, %1" : "+v"(a), "+v"(b));
}
__device__ inline void gll16(const unsigned short* src, void* lds) {
  __builtin_amdgcn_global_load_lds((const __attribute__((address_space(1))) void*)src,
                                   (__attribute__((address_space(3))) void*)lds, 16, 0, 0);
}

// ---------------- kernel 0a: weight casts ----------------
// wcomb[320][256]: rows 0-31 w_q^T*log2e | 32-63 w_k^T | rows 64-319 filled by prep2.
// wv_b[c][m] = wv plain cast; woT_b[e2][e] = wo[e][e2] transposed cast.
__global__ __launch_bounds__(256) void prep_kernel(const float* __restrict__ wq,
                                                   const float* __restrict__ wk,
                                                   const float* __restrict__ wo,
                                                   const float* __restrict__ wv,
                                                   unsigned short* __restrict__ wcomb,
                                                   unsigned short* __restrict__ wv_b,
                                                   unsigned short* __restrict__ woT_b) {
  int i = blockIdx.x * 256 + threadIdx.x;  // total 147456
  if (i < 16384) {
    int row = i >> 8, kk = i & 255;
    float v = (row < 32) ? wq[kk * 32 + row] * LOG2E : wk[kk * 32 + (row - 32)];
    wcomb[i] = f2bf(v);
  } else if (i < 81920) {
    int j = i - 16384;
    wv_b[j] = f2bf(wv[j]);
  } else {
    int j = i - 81920;  // woT_b[e2][e] = wo[e][e2]
    int e2 = j >> 8, e = j & 255;
    woT_b[j] = f2bf(wo[e * 256 + e2]);
  }
}

// ---------------- kernel 0b: Wvo^T = Wo^T . Wv^T  (256x256, K=256) ----------------
// D[e2][c] = sum_e wo[e][e2]*wv[c][e] stored at wcomb[(64+e2)*256 + c].
__global__ __launch_bounds__(256) void prep2_kernel(const unsigned short* __restrict__ woT_b,
                                                    const unsigned short* __restrict__ wv_b,
                                                    unsigned short* __restrict__ wcomb) {
  const int lane = threadIdx.x & 63, w = threadIdx.x >> 6;
  const int g = lane >> 4, li = lane & 15;
  const int m0 = blockIdx.x * 64 + w * 16;
  const unsigned short* arow = woT_b + (size_t)(m0 + li) * 256 + (g << 3);
  const unsigned short* brow = wv_b + (size_t)li * 256 + (g << 3);
  f32x4 acc[16] = {};
  for (int kk = 0; kk < 256; kk += 32) {
    short8 a = *reinterpret_cast<const short8*>(arow + kk);
#pragma unroll
    for (int ct = 0; ct < 16; ++ct) {
      short8 bb = *reinterpret_cast<const short8*>(brow + (size_t)ct * 16 * 256 + kk);
      acc[ct] = __builtin_amdgcn_mfma_f32_16x16x32_bf16(a, bb, acc[ct], 0, 0, 0);
    }
  }
#pragma unroll
  for (int ct = 0; ct < 16; ++ct)
#pragma unroll
    for (int r = 0; r < 4; ++r)
      wcomb[(size_t)(64 + m0 + (g << 2) + r) * 256 + ct * 16 + li] = f2bf(acc[ct][r]);
}

// ---------------- kernel 1: fused QKVW projection (x read once) ----------------
// q,k as before; vw = x . Wvo stored transposed vwT[b][e][n].
__global__ __launch_bounds__(256, 4) void qkv_kernel(const float* __restrict__ x,
                                                     const unsigned short* __restrict__ wcomb,
                                                     unsigned short* __restrict__ q,
                                                     unsigned short* __restrict__ k,
                                                     unsigned short* __restrict__ vwT) {
  const int lane = threadIdx.x & 63, w = threadIdx.x >> 6;
  const int bx = blockIdx.x;
  const int g = lane >> 4, li = lane & 15;
  const int mt = bx * 64 + w * 16;
  const float* xrow = x + (size_t)(mt + li) * 256 + (g << 3);
  const unsigned short* wrow = wcomb + (size_t)li * 256 + (g << 3);
  f32x4 acc[20] = {};
  for (int kk = 0; kk < 256; kk += 32) {
    f32x4 a0 = *reinterpret_cast<const f32x4*>(xrow + kk);
    f32x4 a1 = *reinterpret_cast<const f32x4*>(xrow + kk + 4);
    short8 a;
    a[0] = (short)f2bf(a0[0]); a[1] = (short)f2bf(a0[1]);
    a[2] = (short)f2bf(a0[2]); a[3] = (short)f2bf(a0[3]);
    a[4] = (short)f2bf(a1[0]); a[5] = (short)f2bf(a1[1]);
    a[6] = (short)f2bf(a1[2]); a[7] = (short)f2bf(a1[3]);
#pragma unroll
    for (int ct = 0; ct < 20; ++ct) {
      short8 bb = *reinterpret_cast<const short8*>(wrow + (size_t)ct * 16 * 256 + kk);
      acc[ct] = __builtin_amdgcn_mfma_f32_16x16x32_bf16(a, bb, acc[ct], 0, 0, 0);
    }
  }
  const int bb_ = bx >> 6;
  const int nloc = (bx & 63) * 64 + w * 16 + (g << 2);
#pragma unroll
  for (int ct = 0; ct < 4; ++ct) {
    int col = ct * 16 + li;
    unsigned short* dst = (ct < 2) ? q : k;
    int cc = (ct < 2) ? col : col - 32;
#pragma unroll
    for (int r = 0; r < 4; ++r)
      dst[((size_t)bb_ * N_ + nloc + r) * D_ + cc] = f2bf(acc[ct][r]);
  }
#pragma unroll
  for (int ct = 4; ct < 20; ++ct) {
    int vcol = (ct - 4) * 16 + li;
    ushort4v pk;
    pk[0] = f2bf(acc[ct][0]); pk[1] = f2bf(acc[ct][1]);
    pk[2] = f2bf(acc[ct][2]); pk[3] = f2bf(acc[ct][3]);
    *reinterpret_cast<ushort4v*>(&vwT[((size_t)bb_ * C_ + vcol) * N_ + nloc]) = pk;
  }
}

// ---------------- kernel 2: flash attention + fused output + residual ----------------
// grid 2048 x 64 threads (1 wave/block, 20KB exclusive LDS -> 8 blocks/CU, no barriers).
// blk: b = blk&7 (XCD pin), ch = (blk>>3)&1 (128-c half), qt = blk>>4 (32 q rows).
// Wave walks all 4096 kv in 128 chunks of 32; V[128c][32kv]+K[32kv][32d] double-
// buffered, 2 chunks prefetched ahead via global_load_lds; counted s_waitcnt
// vmcnt(10) (never 0 in steady state). P in registers (swapped S^T=K.Q^T, m=0).
// Epilogue: out = x + O/lsum (fp32) -- output projection already folded into vw.
__global__ __launch_bounds__(64) void flash_kernel(const unsigned short* __restrict__ q,
                                                   const unsigned short* __restrict__ k,
                                                   const unsigned short* __restrict__ vwT,
                                                   const float* __restrict__ x,
                                                   float* __restrict__ out) {
  __shared__ __align__(16) char smem[20480];  // V 2x8192 @0 | K 2x2048 @16384
  const int l = threadIdx.x;
  const int blk = blockIdx.x;
  const int b = blk & 7;
  const int ch = (blk >> 3) & 1;
  const int qt = blk >> 4;  // 0..127
  const int h = l >> 5, l31 = l & 31;

  const unsigned short* kb_ = k + (size_t)b * N_ * D_;
  const unsigned short* vb_ = vwT + (size_t)b * C_ * N_ + (size_t)ch * 128 * N_;

  // Q B-frags: col q = l31, k = ks*16 + 8h + j
  const int qpos = qt * 32 + l31;
  const size_t qoff = ((size_t)b * N_ + qpos) * D_ + h * 8;
  const short8 qb0 = *reinterpret_cast<const short8*>(q + qoff);
  const short8 qb1 = *reinterpret_cast<const short8*>(q + qoff + 16);
  asm volatile("s_waitcnt vmcnt(0)" ::: "memory");  // clean vm counter before staging

  // staging: lane -> (row = l>>2, 16B-block = l&3); source pre-swizzled so LDS
  // block p at row r holds data block p^((r>>1)&3); key reduces to (l>>3)&3.
  const int stg_row = l >> 2;
  const int stg_bk = ((l & 3) ^ ((l >> 3) & 3)) << 3;  // elems

#define STAGE(BUF, KV0)                                                           \
  {                                                                               \
    _Pragma("unroll") for (int t = 0; t < 8; ++t)                                 \
        gll16(vb_ + (size_t)(t * 16 + stg_row) * N_ + (KV0) + stg_bk,             \
              smem + (BUF)*8192 + t * 1024);                                      \
    _Pragma("unroll") for (int t2 = 0; t2 < 2; ++t2)                              \
        gll16(kb_ + (size_t)((KV0) + t2 * 16 + stg_row) * D_ + stg_bk,            \
              smem + 16384 + (BUF)*2048 + t2 * 1024);                             \
  }

  f32x16 o[4] = {};
  float lsum = 0.f;
  const f32x16 z16 = {};

  STAGE(0, 0)
  STAGE(1, 32)

#define BODY(BUF, KVNEXT, WAITN, DOSTAGE)                                              \
  {                                                                                    \
    asm volatile("s_waitcnt vmcnt(" WAITN ")" ::: "memory");                           \
    __builtin_amdgcn_sched_barrier(0);                                                 \
    const char* Kb = smem + 16384 + (BUF)*2048;                                        \
    const char* Vb = smem + (BUF)*8192;                                                \
    const int kkey = (l31 >> 1) & 3;                                                   \
    short8 ka0 = *reinterpret_cast<const short8*>(Kb + l31 * 64 + (((0 + h) ^ kkey) << 4)); \
    short8 ka1 = *reinterpret_cast<const short8*>(Kb + l31 * 64 + (((2 + h) ^ kkey) << 4)); \
    __builtin_amdgcn_sched_barrier(0);                                                 \
    short8 va[4][2];                                                                   \
    _Pragma("unroll") for (int ct = 0; ct < 4; ++ct) {                                 \
      const int rl = ct * 32 + l31;                                                    \
      const int vkey = (rl >> 1) & 3;                                                  \
      va[ct][0] = *reinterpret_cast<const short8*>(Vb + rl * 64 + (((0 + h) ^ vkey) << 4)); \
      va[ct][1] = *reinterpret_cast<const short8*>(Vb + rl * 64 + (((2 + h) ^ vkey) << 4)); \
    }                                                                                  \
    asm volatile("s_waitcnt lgkmcnt(8)" ::: "memory");                                 \
    __builtin_amdgcn_sched_barrier(0);                                                 \
    f32x16 s = __builtin_amdgcn_mfma_f32_32x32x16_bf16(ka0, qb0, z16, 0, 0, 0);        \
    s = __builtin_amdgcn_mfma_f32_32x32x16_bf16(ka1, qb1, s, 0, 0, 0);                 \
    asm volatile("s_waitcnt lgkmcnt(0)" ::: "memory");                                 \
    __builtin_amdgcn_sched_barrier(0);                                                 \
    if (DOSTAGE) STAGE(BUF, KVNEXT)                                                    \
    float p[16];                                                                       \
    _Pragma("unroll") for (int r = 0; r < 16; ++r) p[r] = exp2_fast(s[r]);             \
    lsum += (((p[0] + p[1]) + (p[2] + p[3])) + ((p[4] + p[5]) + (p[6] + p[7]))) +      \
            (((p[8] + p[9]) + (p[10] + p[11])) + ((p[12] + p[13]) + (p[14] + p[15]))); \
    unsigned x0 = cvt_pk_bf16(p[0], p[1]), y0 = cvt_pk_bf16(p[4], p[5]);               \
    unsigned x1 = cvt_pk_bf16(p[2], p[3]), y1 = cvt_pk_bf16(p[6], p[7]);               \
    unsigned x2 = cvt_pk_bf16(p[8], p[9]), y2 = cvt_pk_bf16(p[12], p[13]);             \
    unsigned x3 = cvt_pk_bf16(p[10], p[11]), y3 = cvt_pk_bf16(p[14], p[15]);           \
    permlane32_swap(x0, y0); permlane32_swap(x1, y1);                                  \
    permlane32_swap(x2, y2); permlane32_swap(x3, y3);                                  \
    union U { unsigned u[4]; short8 v; };                                              \
    U u0; u0.u[0] = x0; u0.u[1] = x1; u0.u[2] = y0; u0.u[3] = y1;                      \
    U u1; u1.u[0] = x2; u1.u[1] = x3; u1.u[2] = y2; u1.u[3] = y3;                      \
    __builtin_amdgcn_s_setprio(1);                                                     \
    _Pragma("unroll") for (int ct = 0; ct < 4; ++ct) {                                 \
      o[ct] = __builtin_amdgcn_mfma_f32_32x32x16_bf16(va[ct][0], u0.v, o[ct], 0, 0, 0); \
      o[ct] = __builtin_amdgcn_mfma_f32_32x32x16_bf16(va[ct][1], u1.v, o[ct], 0, 0, 0); \
    }                                                                                  \
    __builtin_amdgcn_s_setprio(0);                                                     \
  }

  for (int i = 0; i < 126; i += 2) {
    BODY(0, (i + 2) * 32, "10", true)
    BODY(1, (i + 3) * 32, "10", true)
  }
  BODY(0, 0, "10", false)  // i = 126 (chunk 127 still in flight)
  BODY(1, 0, "0", false)   // i = 127

  // ---- epilogue: out = x + O/lsum (fp32, full precision residual) ----
  lsum += __shfl_xor(lsum, 32);
  const float inv = 1.0f / lsum;
  const float* xrow = x + ((size_t)b * N_ + qpos) * C_ + ch * 128;
  float* orow = out + ((size_t)b * N_ + qpos) * C_ + ch * 128;
#pragma unroll
  for (int ct = 0; ct < 4; ++ct)
#pragma unroll
    for (int gq = 0; gq < 4; ++gq) {
      const int c = ct * 32 + 8 * gq + 4 * h;
      f32x4 xr = *reinterpret_cast<const f32x4*>(xrow + c);
      f32x4 t;
      t[0] = o[ct][gq * 4 + 0] * inv + xr[0];
      t[1] = o[ct][gq * 4 + 1] * inv + xr[1];
      t[2] = o[ct][gq * 4 + 2] * inv + xr[2];
      t[3] = o[ct][gq * 4 + 3] * inv + xr[3];
      *reinterpret_cast<f32x4*>(orow + c) = t;
    }
#undef BODY
#undef STAGE
}

extern "C" void kernel_launch(void* const* d_in, const int* in_sizes, int n_in,
                              void* d_out, int out_size, void* d_ws, size_t ws_size,
                              hipStream_t stream) {
  const float* x  = (const float*)d_in[0];
  const float* wq = (const float*)d_in[1];
  const float* wk = (const float*)d_in[2];
  const float* wv = (const float*)d_in[3];
  const float* wo = (const float*)d_in[4];
  float* out = (float*)d_out;
  char* ws = (char*)d_ws;
  unsigned short* wcomb = (unsigned short*)(ws + 0);        // 163840 B
  unsigned short* wv_b  = (unsigned short*)(ws + 163840);   // 131072 B
  unsigned short* woT_b = (unsigned short*)(ws + 294912);   // 131072 B
  unsigned short* q     = (unsigned short*)(ws + 425984);   // 2 MB
  unsigned short* k     = (unsigned short*)(ws + 2523136);  // 2 MB
  unsigned short* vwT   = (unsigned short*)(ws + 4620288);  // 16 MB (total ~20.4 MB)

  prep_kernel<<<576, 256, 0, stream>>>(wq, wk, wo, wv, wcomb, wv_b, woT_b);
  prep2_kernel<<<4, 256, 0, stream>>>(woT_b, wv_b, wcomb);
  qkv_kernel<<<512, 256, 0, stream>>>(x, wcomb, q, k, vwT);
  flash_kernel<<<2048, 64, 0, stream>>>(q, k, vwT, x, out);
}

// Round 7
// 189.321 us; speedup vs baseline: 1.2492x; 1.1084x over previous
//
#include <hip/hip_runtime.h>
#include <hip/hip_bf16.h>
#include <stdint.h>

typedef __attribute__((ext_vector_type(8))) short short8;
typedef __attribute__((ext_vector_type(8))) unsigned short ushort8;
typedef __attribute__((ext_vector_type(4))) unsigned short ushort4v;
typedef __attribute__((ext_vector_type(4))) float f32x4;
typedef __attribute__((ext_vector_type(16))) float f32x16;

#define B_ 8
#define N_ 4096
#define C_ 256
#define D_ 32
#define LOG2E 1.44269504088896f

__device__ inline unsigned short f2bf(float f) {
  union { float f; unsigned u; } v; v.f = f;
  unsigned r = v.u + 0x7fffu + ((v.u >> 16) & 1u);
  return (unsigned short)(r >> 16);
}
__device__ inline float exp2_fast(float x) {
  float r; asm("v_exp_f32 %0, %1" : "=v"(r) : "v"(x)); return r;
}
__device__ inline unsigned cvt_pk_bf16(float lo, float hi) {
  unsigned r; asm("v_cvt_pk_bf16_f32 %0, %1, %2" : "=v"(r) : "v"(lo), "v"(hi)); return r;
}
// a <- [a.l0-31 | b.l0-31], b <- [a.l32-63 | b.l32-63]
__device__ inline void permlane32_swap(unsigned& a, unsigned& b) {
  asm volatile("v_permlane32_swap_b32 %0, %1" : "+v"(a), "+v"(b));
}
__device__ inline void gll16(const unsigned short* src, void* lds) {
  __builtin_amdgcn_global_load_lds((const __attribute__((address_space(1))) void*)src,
                                   (__attribute__((address_space(3))) void*)lds, 16, 0, 0);
}

// ---------------- kernel 0a: weight casts ----------------
// wcomb[320][256]: rows 0-31 w_q^T*log2e | 32-63 w_k^T | rows 64-319 filled by prep2.
__global__ __launch_bounds__(256) void prep_kernel(const float* __restrict__ wq,
                                                   const float* __restrict__ wk,
                                                   const float* __restrict__ wo,
                                                   const float* __restrict__ wv,
                                                   unsigned short* __restrict__ wcomb,
                                                   unsigned short* __restrict__ wv_b,
                                                   unsigned short* __restrict__ woT_b) {
  int i = blockIdx.x * 256 + threadIdx.x;  // total 147456
  if (i < 16384) {
    int row = i >> 8, kk = i & 255;
    float v = (row < 32) ? wq[kk * 32 + row] * LOG2E : wk[kk * 32 + (row - 32)];
    wcomb[i] = f2bf(v);
  } else if (i < 81920) {
    int j = i - 16384;
    wv_b[j] = f2bf(wv[j]);
  } else {
    int j = i - 81920;  // woT_b[e2][e] = wo[e][e2]
    int e2 = j >> 8, e = j & 255;
    woT_b[j] = f2bf(wo[e * 256 + e2]);
  }
}

// ---------------- kernel 0b: Wvo^T = Wo^T . Wv^T  (256x256, K=256) ----------------
__global__ __launch_bounds__(256) void prep2_kernel(const unsigned short* __restrict__ woT_b,
                                                    const unsigned short* __restrict__ wv_b,
                                                    unsigned short* __restrict__ wcomb) {
  const int lane = threadIdx.x & 63, w = threadIdx.x >> 6;
  const int g = lane >> 4, li = lane & 15;
  const int m0 = blockIdx.x * 64 + w * 16;
  const unsigned short* arow = woT_b + (size_t)(m0 + li) * 256 + (g << 3);
  const unsigned short* brow = wv_b + (size_t)li * 256 + (g << 3);
  f32x4 acc[16] = {};
  for (int kk = 0; kk < 256; kk += 32) {
    short8 a = *reinterpret_cast<const short8*>(arow + kk);
#pragma unroll
    for (int ct = 0; ct < 16; ++ct) {
      short8 bb = *reinterpret_cast<const short8*>(brow + (size_t)ct * 16 * 256 + kk);
      acc[ct] = __builtin_amdgcn_mfma_f32_16x16x32_bf16(a, bb, acc[ct], 0, 0, 0);
    }
  }
#pragma unroll
  for (int ct = 0; ct < 16; ++ct)
#pragma unroll
    for (int r = 0; r < 4; ++r)
      wcomb[(size_t)(64 + m0 + (g << 2) + r) * 256 + ct * 16 + li] = f2bf(acc[ct][r]);
}

// ---------------- kernel 1: fused QKVW projection (x read once) ----------------
__global__ __launch_bounds__(256, 4) void qkv_kernel(const float* __restrict__ x,
                                                     const unsigned short* __restrict__ wcomb,
                                                     unsigned short* __restrict__ q,
                                                     unsigned short* __restrict__ k,
                                                     unsigned short* __restrict__ vwT) {
  const int lane = threadIdx.x & 63, w = threadIdx.x >> 6;
  const int bx = blockIdx.x;
  const int g = lane >> 4, li = lane & 15;
  const int mt = bx * 64 + w * 16;
  const float* xrow = x + (size_t)(mt + li) * 256 + (g << 3);
  const unsigned short* wrow = wcomb + (size_t)li * 256 + (g << 3);
  f32x4 acc[20] = {};
  for (int kk = 0; kk < 256; kk += 32) {
    f32x4 a0 = *reinterpret_cast<const f32x4*>(xrow + kk);
    f32x4 a1 = *reinterpret_cast<const f32x4*>(xrow + kk + 4);
    short8 a;
    a[0] = (short)f2bf(a0[0]); a[1] = (short)f2bf(a0[1]);
    a[2] = (short)f2bf(a0[2]); a[3] = (short)f2bf(a0[3]);
    a[4] = (short)f2bf(a1[0]); a[5] = (short)f2bf(a1[1]);
    a[6] = (short)f2bf(a1[2]); a[7] = (short)f2bf(a1[3]);
#pragma unroll
    for (int ct = 0; ct < 20; ++ct) {
      short8 bb = *reinterpret_cast<const short8*>(wrow + (size_t)ct * 16 * 256 + kk);
      acc[ct] = __builtin_amdgcn_mfma_f32_16x16x32_bf16(a, bb, acc[ct], 0, 0, 0);
    }
  }
  const int bb_ = bx >> 6;
  const int nloc = (bx & 63) * 64 + w * 16 + (g << 2);
#pragma unroll
  for (int ct = 0; ct < 4; ++ct) {
    int col = ct * 16 + li;
    unsigned short* dst = (ct < 2) ? q : k;
    int cc = (ct < 2) ? col : col - 32;
#pragma unroll
    for (int r = 0; r < 4; ++r)
      dst[((size_t)bb_ * N_ + nloc + r) * D_ + cc] = f2bf(acc[ct][r]);
  }
#pragma unroll
  for (int ct = 4; ct < 20; ++ct) {
    int vcol = (ct - 4) * 16 + li;
    ushort4v pk;
    pk[0] = f2bf(acc[ct][0]); pk[1] = f2bf(acc[ct][1]);
    pk[2] = f2bf(acc[ct][2]); pk[3] = f2bf(acc[ct][3]);
    *reinterpret_cast<ushort4v*>(&vwT[((size_t)bb_ * C_ + vcol) * N_ + nloc]) = pk;
  }
}

// ---------------- kernel 2: flash attention + fused output + residual ----------------
// grid 512 x 256 threads. blk: b = blk&7 (XCD pin), qt = blk>>3 (64 q rows).
// 4 waves: qs = w>>1 (32q subtile), ch = w&1 (128c half for PV/output).
// Chunk = 32 kv, TRIPLE-buffered V[256c][32kv] (16KB) + K[32][32d] (2KB):
// iter i consumes buf i%3, stages chunk i+2 into (i+2)%3 -- never the buffer
// being read, so compute needs NO lgkm fences. Per iter: counted s_waitcnt
// vmcnt(own L, never 0) -> one raw s_barrier -> fire stage -> register compute.
// P in registers (swapped S^T=K.Q^T, fixed m=0, q pre-scaled log2e); output
// projection folded into vwT; epilogue out = x + O/lsum.
__global__ __launch_bounds__(256, 2) void flash_kernel(const unsigned short* __restrict__ q,
                                                       const unsigned short* __restrict__ k,
                                                       const unsigned short* __restrict__ vwT,
                                                       const float* __restrict__ x,
                                                       float* __restrict__ out) {
  __shared__ __align__(16) char smem[55296];  // V 3x16384 @0 | K 3x2048 @49152
  const int tid = threadIdx.x;
  const int l = tid & 63, w_ = tid >> 6;
  const int qs = w_ >> 1, ch = w_ & 1;
  const int blk = blockIdx.x;
  const int b = blk & 7;
  const int qt = blk >> 3;  // 0..63
  const int h = l >> 5, l31 = l & 31;

  const unsigned short* kb_ = k + (size_t)b * N_ * D_;
  const unsigned short* vb_ = vwT + (size_t)b * C_ * N_;

  // Q B-frags: col q = l31, k = ks*16 + 8h + j
  const int qpos = qt * 64 + qs * 32 + l31;
  const size_t qoff = ((size_t)b * N_ + qpos) * D_ + h * 8;
  const short8 qb0 = *reinterpret_cast<const short8*>(q + qoff);
  const short8 qb1 = *reinterpret_cast<const short8*>(q + qoff + 16);
  asm volatile("s_waitcnt vmcnt(0)" ::: "memory");  // clean vm counter before staging

  // staging: 1KB gll16 covers 16 rows x 64B; lane -> (row = l>>2, 16B-blk = l&3);
  // source pre-swizzled so LDS block p at row r holds data block p^((r>>1)&3).
  const int stg_row = l >> 2;
  const int stg_bk = ((l & 3) ^ ((l >> 3) & 3)) << 3;  // elems

  // wave stages V rows w_*64..+63 (4 gll16); waves 0,1 also stage 16 K rows each.
#define STAGE(BUF, KV0)                                                         \
  {                                                                             \
    char* vd = smem + (BUF) * 16384 + w_ * 4096;                                \
    _Pragma("unroll") for (int t = 0; t < 4; ++t)                               \
        gll16(vb_ + (size_t)(w_ * 64 + t * 16 + stg_row) * N_ + (KV0) + stg_bk, \
              vd + t * 1024);                                                   \
    if (w_ < 2)                                                                 \
      gll16(kb_ + (size_t)((KV0) + w_ * 16 + stg_row) * D_ + stg_bk,            \
            smem + 49152 + (BUF) * 2048 + w_ * 1024);                           \
  }

  f32x16 o[4] = {};  // O^T (32c x 32q) per ct, c range = ch*128 + ct*32
  float lsum = 0.f;
  const f32x16 z16 = {};

  STAGE(0, 0)
  STAGE(1, 32)

  int cur = 0, nxt = 2;
  for (int i = 0; i < 128; ++i) {
    // own chunk-i loads done (chunk i+1's stay in flight; drain only at the end)
    if (i < 127) {
      if (w_ < 2) asm volatile("s_waitcnt vmcnt(5)" ::: "memory");
      else        asm volatile("s_waitcnt vmcnt(4)" ::: "memory");
    } else {
      asm volatile("s_waitcnt vmcnt(0)" ::: "memory");
    }
    __builtin_amdgcn_sched_barrier(0);
    __builtin_amdgcn_s_barrier();  // all waves: chunk i landed; prev iter's reads done
    if (i < 126) STAGE(nxt, (i + 2) * 32)
    const char* Vb = smem + cur * 16384;
    const char* Kb = smem + 49152 + cur * 2048;
    // ---- S^T[32kv][32q] = K . Q^T ----
    const int kkey = (l31 >> 1) & 3;
    short8 ka0 = *reinterpret_cast<const short8*>(Kb + l31 * 64 + (((0 + h) ^ kkey) << 4));
    short8 ka1 = *reinterpret_cast<const short8*>(Kb + l31 * 64 + (((2 + h) ^ kkey) << 4));
    f32x16 s = __builtin_amdgcn_mfma_f32_32x32x16_bf16(ka0, qb0, z16, 0, 0, 0);
    s = __builtin_amdgcn_mfma_f32_32x32x16_bf16(ka1, qb1, s, 0, 0, 0);
    float p[16];
#pragma unroll
    for (int r = 0; r < 16; ++r) p[r] = exp2_fast(s[r]);
    lsum += (((p[0] + p[1]) + (p[2] + p[3])) + ((p[4] + p[5]) + (p[6] + p[7]))) +
            (((p[8] + p[9]) + (p[10] + p[11])) + ((p[12] + p[13]) + (p[14] + p[15])));
    unsigned x0 = cvt_pk_bf16(p[0], p[1]),   y0 = cvt_pk_bf16(p[4], p[5]);
    unsigned x1 = cvt_pk_bf16(p[2], p[3]),   y1 = cvt_pk_bf16(p[6], p[7]);
    unsigned x2 = cvt_pk_bf16(p[8], p[9]),   y2 = cvt_pk_bf16(p[12], p[13]);
    unsigned x3 = cvt_pk_bf16(p[10], p[11]), y3 = cvt_pk_bf16(p[14], p[15]);
    permlane32_swap(x0, y0); permlane32_swap(x1, y1);
    permlane32_swap(x2, y2); permlane32_swap(x3, y3);
    union U { unsigned u[4]; short8 v; };
    U u0; u0.u[0] = x0; u0.u[1] = x1; u0.u[2] = y0; u0.u[3] = y1;  // kv 0-15
    U u1; u1.u[0] = x2; u1.u[1] = x3; u1.u[2] = y2; u1.u[3] = y3;  // kv 16-31
    // ---- PV: O^T[c][q] += V^T . P^T ----
    __builtin_amdgcn_s_setprio(1);
#pragma unroll
    for (int ct = 0; ct < 4; ++ct) {
      const int rl = ch * 128 + ct * 32 + l31;
      const int vkey = (rl >> 1) & 3;
      short8 va0 = *reinterpret_cast<const short8*>(Vb + rl * 64 + (((0 + h) ^ vkey) << 4));
      short8 va1 = *reinterpret_cast<const short8*>(Vb + rl * 64 + (((2 + h) ^ vkey) << 4));
      o[ct] = __builtin_amdgcn_mfma_f32_32x32x16_bf16(va0, u0.v, o[ct], 0, 0, 0);
      o[ct] = __builtin_amdgcn_mfma_f32_32x32x16_bf16(va1, u1.v, o[ct], 0, 0, 0);
    }
    __builtin_amdgcn_s_setprio(0);
    cur = (cur == 2) ? 0 : cur + 1;
    nxt = (nxt == 2) ? 0 : nxt + 1;
  }

  // ---- epilogue: out = x + O/lsum (fp32 residual) ----
  lsum += __shfl_xor(lsum, 32);
  const float inv = 1.0f / lsum;
  const float* xrow = x + ((size_t)b * N_ + qpos) * C_ + ch * 128;
  float* orow = out + ((size_t)b * N_ + qpos) * C_ + ch * 128;
#pragma unroll
  for (int ct = 0; ct < 4; ++ct)
#pragma unroll
    for (int gq = 0; gq < 4; ++gq) {
      const int c = ct * 32 + 8 * gq + 4 * h;
      f32x4 xr = *reinterpret_cast<const f32x4*>(xrow + c);
      f32x4 t;
      t[0] = o[ct][gq * 4 + 0] * inv + xr[0];
      t[1] = o[ct][gq * 4 + 1] * inv + xr[1];
      t[2] = o[ct][gq * 4 + 2] * inv + xr[2];
      t[3] = o[ct][gq * 4 + 3] * inv + xr[3];
      *reinterpret_cast<f32x4*>(orow + c) = t;
    }
#undef STAGE
}

extern "C" void kernel_launch(void* const* d_in, const int* in_sizes, int n_in,
                              void* d_out, int out_size, void* d_ws, size_t ws_size,
                              hipStream_t stream) {
  const float* x  = (const float*)d_in[0];
  const float* wq = (const float*)d_in[1];
  const float* wk = (const float*)d_in[2];
  const float* wv = (const float*)d_in[3];
  const float* wo = (const float*)d_in[4];
  float* out = (float*)d_out;
  char* ws = (char*)d_ws;
  unsigned short* wcomb = (unsigned short*)(ws + 0);        // 163840 B
  unsigned short* wv_b  = (unsigned short*)(ws + 163840);   // 131072 B
  unsigned short* woT_b = (unsigned short*)(ws + 294912);   // 131072 B
  unsigned short* q     = (unsigned short*)(ws + 425984);   // 2 MB
  unsigned short* k     = (unsigned short*)(ws + 2523136);  // 2 MB
  unsigned short* vwT   = (unsigned short*)(ws + 4620288);  // 16 MB (total ~20.4 MB)

  prep_kernel<<<576, 256, 0, stream>>>(wq, wk, wo, wv, wcomb, wv_b, woT_b);
  prep2_kernel<<<4, 256, 0, stream>>>(woT_b, wv_b, wcomb);
  qkv_kernel<<<512, 256, 0, stream>>>(x, wcomb, q, k, vwT);
  flash_kernel<<<512, 256, 0, stream>>>(q, k, vwT, x, out);
}